// Round 9
// baseline (337.445 us; speedup 1.0000x reference)
//
#include <hip/hip_runtime.h>
#include <stdint.h>

typedef _Float16 f16;
typedef f16 f16x8 __attribute__((ext_vector_type(8)));
typedef float f32x4 __attribute__((ext_vector_type(4)));

#define MFMA(a,b,c) __builtin_amdgcn_mfma_f32_16x16x32_f16(a, b, c, 0, 0, 0)

__device__ __forceinline__ float sigmoidf_(float z) {
  return __builtin_amdgcn_rcpf(1.0f + __expf(-z));
}

// load 8 consecutive f32 and convert to f16x8 (weights are L2-resident)
__device__ __forceinline__ f16x8 ldw8(const float* __restrict__ p) {
  union { uint4 u; float f[4]; } a, bqq;
  a.u  = *(const uint4*)p;
  bqq.u = *(const uint4*)(p + 4);
  f16x8 r;
  r[0] = (f16)a.f[0];  r[1] = (f16)a.f[1];  r[2] = (f16)a.f[2];  r[3] = (f16)a.f[3];
  r[4] = (f16)bqq.f[0]; r[5] = (f16)bqq.f[1]; r[6] = (f16)bqq.f[2]; r[7] = (f16)bqq.f[3];
  return r;
}

// device-scope grid barrier: all 256 blocks co-resident (1 block/CU by LDS).
__device__ __forceinline__ void grid_bar(uint32_t* bar, uint32_t target) {
  __syncthreads();
  if (threadIdx.x == 0) {
    __threadfence();                 // release: push M writes out of this XCD's L2
    atomicAdd(bar, 1u);
    while (__hip_atomic_load(bar, __ATOMIC_ACQUIRE, __HIP_MEMORY_SCOPE_AGENT) < target)
      __builtin_amdgcn_s_sleep(2);
    __threadfence();                 // acquire: invalidate stale lines
  }
  __syncthreads();
}

// ---------------------------------------------------------------------------
// prep: Wcat = [Aq;Ak;Av] (192x2048) f32->f16; zero out[0..63] and barrier.
// ---------------------------------------------------------------------------
__global__ void prep_kernel(const float* __restrict__ Aq, const float* __restrict__ Ak,
                            const float* __restrict__ Av, f16* __restrict__ Wcat,
                            uint32_t* __restrict__ bar, float* __restrict__ out)
{
  int blk = blockIdx.x, t = threadIdx.x;
  if (blk < 96) {
    int base = blk * 4096;
    for (int i = 0; i < 16; i++) {
      int idx = base + t + i * 256;
      int row = idx >> 11, col = idx & 2047;
      float v = (row < 64) ? Aq[row * 2048 + col]
              : (row < 128) ? Ak[(row - 64) * 2048 + col]
              : Av[(row - 128) * 2048 + col];
      Wcat[idx] = (f16)v;
    }
  } else {
    if (t < 64) out[t] = 0.0f;
    if (t == 64) *bar = 0u;
  }
}

// ---------------------------------------------------------------------------
// qkv1 v7: K-chunk 128 -> 16 barrier iterations (was 32). Empirical law from
// R3/R6/R7: cost ~2.2us PER ITERATION regardless of structure; halving the
// iteration count is the only lever that tracked. Tile 64n x 192r, 512 thr
// (8 waves: nh=w>>2 n-half, wr_=w&3 r-strip). LDS 132 KB dbuf -> 1 blk/CU.
// T14 split with named regs (16 x-floats + 6 uint4 W), ONE barrier/iter.
// ---------------------------------------------------------------------------
__global__ __launch_bounds__(512) void qkv1_kernel(const float* __restrict__ x,
    const f16* __restrict__ Wcat, f16* __restrict__ Qt, f16* __restrict__ Kt,
    f16* __restrict__ Vg)
{
  int b = blockIdx.y, n0 = blockIdx.x * 64;
  int t = threadIdx.x, lane = t & 63, w = t >> 6;   // 8 waves
  int l15 = lane & 15, q = lane >> 4;
  int nh = w >> 2, wr_ = w & 3;
  __shared__ f16 xt[2][64 * 132];    // x^T tile [n][f], stride 132
  __shared__ f16 wt[2][192 * 132];   // W tile [r][f]
  f32x4 acc[2][3] = {};
  const float* xb = x + (size_t)b * 524288 + n0;
  int tn = lane;
  const float* px = xb + (size_t)(w * 16) * 256 + tn;   // wave w: f-rows w*16..+15

  // W staging: 192 rows x 16 uint4-cols = 3072 uint4; 6 per thread
  int r0 = t >> 4,           c0 = t & 15;
  int r1 = (t + 512) >> 4,   c1 = (t + 512) & 15;
  int r2 = (t + 1024) >> 4,  c2 = (t + 1024) & 15;
  int r3 = (t + 1536) >> 4,  c3 = (t + 1536) & 15;
  int r4 = (t + 2048) >> 4,  c4 = (t + 2048) & 15;
  int r5 = (t + 2560) >> 4,  c5 = (t + 2560) & 15;
  const f16* pw0 = Wcat + (size_t)r0 * 2048 + c0 * 8;
  const f16* pw1 = Wcat + (size_t)r1 * 2048 + c1 * 8;
  const f16* pw2 = Wcat + (size_t)r2 * 2048 + c2 * 8;
  const f16* pw3 = Wcat + (size_t)r3 * 2048 + c3 * 8;
  const f16* pw4 = Wcat + (size_t)r4 * 2048 + c4 * 8;
  const f16* pw5 = Wcat + (size_t)r5 * 2048 + c5 * 8;

  float xa0, xa1, xa2, xa3, xa4, xa5, xa6, xa7;
  float xa8, xa9, xa10, xa11, xa12, xa13, xa14, xa15;
  uint4 wv0, wv1, wv2, wv3, wv4, wv5;

#define LOAD_XW(f0n) do {                                                       \
    const float* p_ = px + (size_t)(f0n) * 256;                                 \
    xa0  = p_[0];    xa1  = p_[256];  xa2  = p_[512];  xa3  = p_[768];          \
    xa4  = p_[1024]; xa5  = p_[1280]; xa6  = p_[1536]; xa7  = p_[1792];         \
    xa8  = p_[2048]; xa9  = p_[2304]; xa10 = p_[2560]; xa11 = p_[2816];         \
    xa12 = p_[3072]; xa13 = p_[3328]; xa14 = p_[3584]; xa15 = p_[3840];         \
    wv0 = *(const uint4*)(pw0 + (f0n)); wv1 = *(const uint4*)(pw1 + (f0n));     \
    wv2 = *(const uint4*)(pw2 + (f0n)); wv3 = *(const uint4*)(pw3 + (f0n));     \
    wv4 = *(const uint4*)(pw4 + (f0n)); wv5 = *(const uint4*)(pw5 + (f0n));     \
  } while (0)

#define WRITE_XW(buf) do {                                                      \
    f16x8 pa_, pb_;                                                             \
    pa_[0] = (f16)xa0;  pa_[1] = (f16)xa1;  pa_[2] = (f16)xa2;  pa_[3] = (f16)xa3;  \
    pa_[4] = (f16)xa4;  pa_[5] = (f16)xa5;  pa_[6] = (f16)xa6;  pa_[7] = (f16)xa7;  \
    pb_[0] = (f16)xa8;  pb_[1] = (f16)xa9;  pb_[2] = (f16)xa10; pb_[3] = (f16)xa11; \
    pb_[4] = (f16)xa12; pb_[5] = (f16)xa13; pb_[6] = (f16)xa14; pb_[7] = (f16)xa15; \
    *(f16x8*)&xt[buf][tn * 132 + w * 16]     = pa_;                             \
    *(f16x8*)&xt[buf][tn * 132 + w * 16 + 8] = pb_;                             \
    f16* wb_ = &wt[buf][0];                                                     \
    *(uint4*)&wb_[r0 * 132 + c0 * 8] = wv0;                                     \
    *(uint4*)&wb_[r1 * 132 + c1 * 8] = wv1;                                     \
    *(uint4*)&wb_[r2 * 132 + c2 * 8] = wv2;                                     \
    *(uint4*)&wb_[r3 * 132 + c3 * 8] = wv3;                                     \
    *(uint4*)&wb_[r4 * 132 + c4 * 8] = wv4;                                     \
    *(uint4*)&wb_[r5 * 132 + c5 * 8] = wv5;                                     \
  } while (0)

  LOAD_XW(0);
  WRITE_XW(0);
  __syncthreads();

  int cur = 0;
  for (int f0 = 0; f0 < 2048; f0 += 128) {
    int nxt = cur ^ 1;
    bool more = (f0 + 128 < 2048);
    if (more) LOAD_XW(f0 + 128);    // next chunk's HBM latency hides under 24 MFMAs

    #pragma unroll
    for (int ks = 0; ks < 4; ks++) {
      int k0 = ks * 32 + q * 8;
      f16x8 af[2], bf[3];
      af[0] = *(const f16x8*)&xt[cur][(nh * 32 + l15) * 132 + k0];
      af[1] = *(const f16x8*)&xt[cur][(nh * 32 + 16 + l15) * 132 + k0];
      #pragma unroll
      for (int j = 0; j < 3; j++)
        bf[j] = *(const f16x8*)&wt[cur][((wr_ * 3 + j) * 16 + l15) * 132 + k0];
      #pragma unroll
      for (int nt = 0; nt < 2; nt++)
        #pragma unroll
        for (int j = 0; j < 3; j++)
          acc[nt][j] = MFMA(af[nt], bf[j], acc[nt][j]);
    }

    if (more) WRITE_XW(nxt);
    __syncthreads();
    cur = nxt;
  }
#undef LOAD_XW
#undef WRITE_XW

  #pragma unroll
  for (int nt = 0; nt < 2; nt++)
    #pragma unroll
    for (int j = 0; j < 3; j++) {
      int rr = (wr_ * 3 + j) * 16 + l15;
      float s[4];
      #pragma unroll
      for (int reg = 0; reg < 4; reg++) s[reg] = sigmoidf_(acc[nt][j][reg]);
      int nbase = n0 + nh * 32 + nt * 16 + q * 4;
      if (rr < 64) {
        #pragma unroll
        for (int reg = 0; reg < 4; reg++)
          Qt[(size_t)b * 16384 + (size_t)(nbase + reg) * 64 + rr] = (f16)s[reg];
      } else if (rr < 128) {
        #pragma unroll
        for (int reg = 0; reg < 4; reg++)
          Kt[(size_t)b * 16384 + (size_t)(nbase + reg) * 64 + (rr - 64)] = (f16)s[reg];
      } else {
        union { f16 h[4]; uint2 u; } pk;
        #pragma unroll
        for (int reg = 0; reg < 4; reg++) pk.h[reg] = (f16)s[reg];
        *(uint2*)(Vg + (size_t)b * 16384 + (size_t)(rr - 128) * 256 + nbase) = pk.u;
      }
    }
}

// ---------------------------------------------------------------------------
// attn_fused: ALL THREE attention layers in one kernel. grid (4,64) = 256
// blocks = 1 block/CU (LDS ~132 KB), 1024 thr (16 waves). Layers separated by
// a device-scope grid barrier (M handoff through global + __threadfence).
// scale[b] computed per-block from L; small weights read directly as f32 with
// in-register cvt (Wsm eliminated); quad-epilogue x values prefetched at entry.
// Phase bodies identical to the verified R8 kernel (strides 76/268/68).
// ---------------------------------------------------------------------------
__global__ __launch_bounds__(1024) void attn_fused_kernel(const float* __restrict__ x,
    const float* __restrict__ L,
    const float* __restrict__ Aq1, const float* __restrict__ Ak1, const float* __restrict__ Av1,
    const float* __restrict__ Aq5, const float* __restrict__ Ak5, const float* __restrict__ Av5,
    const float* __restrict__ Ao, const float* __restrict__ Ao1, const float* __restrict__ Ao5,
    const f16* __restrict__ Qtg, const f16* __restrict__ Ktg, const f16* __restrict__ Vgg,
    f16* __restrict__ MbufA, f16* __restrict__ MbufB,
    uint32_t* __restrict__ bar, float* __restrict__ out)
{
  int g = blockIdx.x, b = blockIdx.y, n0 = g * 64;
  int t = threadIdx.x, lane = t & 63, w = t >> 6;    // 16 waves
  int l15 = lane & 15, q = lane >> 4;
  __shared__ f16 KT[256 * 76];
  __shared__ f16 SM[256 * 76];   // M^T staging (stride 76) / S4 (stride 268)
  __shared__ f16 VM[64 * 268];
  __shared__ f16 QT[64 * 76];    // later M' staging at stride 68
  __shared__ f16 OT[64 * 76];
  __shared__ float denomS[64];
  __shared__ float scpart[9];

  // ---- scale[b] from L (per-block, no global round-trip) ----
  float sv = 0.0f;
  if (t < 512) sv = (L[(size_t)b * 512 + t] >= 1.0f) ? 1.0f : 0.0f;
  #pragma unroll
  for (int off = 32; off; off >>= 1) sv += __shfl_down(sv, off);
  if (w < 8 && lane == 0) scpart[w] = sv;
  __syncthreads();
  if (t == 0) {
    float s = scpart[0] + scpart[1] + scpart[2] + scpart[3]
            + scpart[4] + scpart[5] + scpart[6] + scpart[7];
    scpart[8] = __builtin_amdgcn_rcpf(sqrtf(s + 1.0f));
  }
  __syncthreads();
  float sinv = scpart[8];

  // ---- quad-epilogue x prefetch (t<64 only; latency hides under everything) ----
  float q1a = 0.f, q1b = 0.f, q2a = 0.f, q2b = 0.f;
  if (t < 64) {
    int ntok = n0 + t, np = ntok >> 1, c0e = (ntok & 1) * 2;
    const float* xbq = x + (size_t)b * 524288 + (size_t)c0e * 256;
    q1a = xbq[np]; q1b = xbq[256 + np]; q2a = xbq[128 + np]; q2b = xbq[384 + np];
  }

  f16x8 bkav[4][2], wqa, wqb;

  for (int l = 0; l < 3; ++l) {
    const float* Wqf = (l == 1) ? Aq1 : Aq5;
    const float* Wkf = (l == 1) ? Ak1 : Ak5;
    const float* Wvf = (l == 1) ? Av1 : Av5;
    const float* Wof = (l == 0) ? Ao : (l == 1) ? Ao1 : Ao5;
    const f16* Min = (l == 1) ? MbufA : MbufB;
    f16* Mout = (l == 0) ? MbufA : MbufB;

    if (t < 64) denomS[t] = 0.0f;

    if (l > 0) {
      // early weight-fragment prefetch (f32 -> f16 in-register)
      const float* Wrole = (w < 8) ? Wkf : Wvf;
      #pragma unroll
      for (int rt = 0; rt < 4; rt++) {
        bkav[rt][0] = ldw8(Wrole + (rt * 16 + l15) * 64 + q * 8);
        bkav[rt][1] = ldw8(Wrole + (rt * 16 + l15) * 64 + 32 + q * 8);
      }
      int rtq = w & 3;
      wqa = ldw8(Wqf + (rtq * 16 + l15) * 64 + q * 8);
      wqb = ldw8(Wqf + (rtq * 16 + l15) * 64 + 32 + q * 8);
    }

    if (l == 0) {
      if (t < 512) {
        const uint4* qs = (const uint4*)(Qtg + (size_t)b * 16384 + (size_t)n0 * 64);
        int n = t >> 3, c = t & 7; *(uint4*)&QT[n * 76 + c * 8] = qs[t];
      }
      const uint4* ks = (const uint4*)(Ktg + (size_t)b * 16384);
      const uint4* vs = (const uint4*)(Vgg + (size_t)b * 16384);
      #pragma unroll
      for (int i = 0; i < 2; i++) {
        int id = t + i * 1024;
        int m = id >> 3, c = id & 7;
        *(uint4*)&KT[m * 76 + c * 8] = ks[id];
        int r = id >> 5, c2 = id & 31;
        *(uint4*)&VM[r * 268 + c2 * 8] = vs[id];
      }
    } else {
      const uint4* ms = (const uint4*)(Min + (size_t)b * 16384);
      #pragma unroll
      for (int i = 0; i < 2; i++) {
        int id = t + i * 1024, m = id >> 3, c = id & 7;
        *(uint4*)&SM[m * 76 + c * 8] = ms[id];
      }
    }
    __syncthreads();

    if (l > 0) {
      if (w < 8) {
        #pragma unroll
        for (int mi = 0; mi < 2; mi++) {
          int mt = w * 2 + mi;
          f16x8 a0 = *(const f16x8*)&SM[(mt * 16 + l15) * 76 + q * 8];
          f16x8 a1 = *(const f16x8*)&SM[(mt * 16 + l15) * 76 + 32 + q * 8];
          #pragma unroll
          for (int rt = 0; rt < 4; rt++) {
            f32x4 acc = {}; acc = MFMA(a0, bkav[rt][0], acc); acc = MFMA(a1, bkav[rt][1], acc);
            #pragma unroll
            for (int reg = 0; reg < 4; reg++)
              KT[(mt * 16 + q * 4 + reg) * 76 + rt * 16 + l15] = (f16)sigmoidf_(acc[reg]);
          }
        }
      } else {
        #pragma unroll
        for (int mi = 0; mi < 2; mi++) {
          int mt = (w - 8) * 2 + mi;
          f16x8 b0 = *(const f16x8*)&SM[(mt * 16 + l15) * 76 + q * 8];
          f16x8 b1 = *(const f16x8*)&SM[(mt * 16 + l15) * 76 + 32 + q * 8];
          #pragma unroll
          for (int rt = 0; rt < 4; rt++) {
            f32x4 acc = {}; acc = MFMA(bkav[rt][0], b0, acc); acc = MFMA(bkav[rt][1], b1, acc);
            #pragma unroll
            for (int reg = 0; reg < 4; reg++)
              VM[(rt * 16 + q * 4 + reg) * 268 + mt * 16 + l15] = (f16)sigmoidf_(acc[reg]);
          }
        }
      }
      {
        int nt = w >> 2, rt = w & 3;
        f16x8 a0 = *(const f16x8*)&SM[(n0 + nt * 16 + l15) * 76 + q * 8];
        f16x8 a1 = *(const f16x8*)&SM[(n0 + nt * 16 + l15) * 76 + 32 + q * 8];
        f32x4 acc = {}; acc = MFMA(a0, wqa, acc); acc = MFMA(a1, wqb, acc);
        #pragma unroll
        for (int reg = 0; reg < 4; reg++)
          QT[(nt * 16 + q * 4 + reg) * 76 + rt * 16 + l15] = (f16)sigmoidf_(acc[reg]);
      }
      __syncthreads();
    }

    // S = exp(QK^T * sinv)
    {
      int nt = w >> 2;
      f16x8 a0 = *(const f16x8*)&QT[(nt * 16 + l15) * 76 + q * 8];
      f16x8 a1 = *(const f16x8*)&QT[(nt * 16 + l15) * 76 + 32 + q * 8];
      float dsum[4] = {0.f, 0.f, 0.f, 0.f};
      #pragma unroll
      for (int mi = 0; mi < 4; mi++) {
        int mt = (w & 3) * 4 + mi;
        f16x8 b0 = *(const f16x8*)&KT[(mt * 16 + l15) * 76 + q * 8];
        f16x8 b1 = *(const f16x8*)&KT[(mt * 16 + l15) * 76 + 32 + q * 8];
        f32x4 acc = {}; acc = MFMA(a0, b0, acc); acc = MFMA(a1, b1, acc);
        #pragma unroll
        for (int reg = 0; reg < 4; reg++) {
          float e = __expf(acc[reg] * sinv);
          dsum[reg] += e;
          SM[(nt * 16 + q * 4 + reg) * 268 + mt * 16 + l15] = (f16)e;
        }
      }
      #pragma unroll
      for (int reg = 0; reg < 4; reg++) {
        #pragma unroll
        for (int mask = 1; mask < 16; mask <<= 1) dsum[reg] += __shfl_xor(dsum[reg], mask);
      }
      if (l15 == 0) {
        #pragma unroll
        for (int reg = 0; reg < 4; reg++) atomicAdd(&denomS[nt * 16 + q * 4 + reg], dsum[reg]);
      }
    }
    __syncthreads();

    // AV
    {
      int nt = w >> 2, rt = w & 3;
      f32x4 oacc = {};
      #pragma unroll
      for (int kc = 0; kc < 8; kc++) {
        f16x8 af = *(const f16x8*)&SM[(nt * 16 + l15) * 268 + kc * 32 + q * 8];
        f16x8 bf = *(const f16x8*)&VM[(rt * 16 + l15) * 268 + kc * 32 + q * 8];
        oacc = MFMA(af, bf, oacc);
      }
      float rden[4];
      #pragma unroll
      for (int reg = 0; reg < 4; reg++)
        rden[reg] = __builtin_amdgcn_rcpf(denomS[nt * 16 + q * 4 + reg]);
      #pragma unroll
      for (int reg = 0; reg < 4; reg++) {
        int row = nt * 16 + q * 4 + reg;
        OT[row * 76 + rt * 16 + l15] = (f16)(oacc[reg] * rden[reg]);
      }
    }
    __syncthreads();

    // M' = silu(OT * Wo^T) -> Mst (QT reused, stride 68)
    f16* Mst = QT;
    {
      int nt = w >> 2, st = w & 3;
      f16x8 a0 = *(const f16x8*)&OT[(nt * 16 + l15) * 76 + q * 8];
      f16x8 a1 = *(const f16x8*)&OT[(nt * 16 + l15) * 76 + 32 + q * 8];
      f16x8 b0 = ldw8(Wof + (st * 16 + l15) * 64 + q * 8);
      f16x8 b1 = ldw8(Wof + (st * 16 + l15) * 64 + 32 + q * 8);
      f32x4 acc = {}; acc = MFMA(a0, b0, acc); acc = MFMA(a1, b1, acc);
      #pragma unroll
      for (int reg = 0; reg < 4; reg++) {
        float z = acc[reg];
        Mst[(nt * 16 + q * 4 + reg) * 68 + st * 16 + l15] = (f16)(z * sigmoidf_(z));
      }
    }
    __syncthreads();

    if (l < 2) {
      if (t < 512) {
        int row = t >> 3, c = t & 7;
        *(uint4*)(Mout + (size_t)b * 16384 + (size_t)(n0 + row) * 64 + c * 8)
            = *(const uint4*)&Mst[row * 68 + c * 8];
      }
      grid_bar(bar, 256u * (uint32_t)(l + 1));
    } else {
      float contrib = 0.0f;
      if (t < 64) {
        const f16* row = &Mst[t * 68];
        float d[4] = {0, 0, 0, 0}, pp = 0.0f;
        #pragma unroll
        for (int gg = 0; gg < 8; gg++) {
          f16x8 v = *(const f16x8*)(row + gg * 8);
          float ss = 0.0f;
          #pragma unroll
          for (int k = 0; k < 8; k++) { float f = (float)v[k]; ss += f * f; }
          if (gg < 4) d[gg] = ss; else pp += ss;
        }
        contrib = d[0] * (q1a * q1a + q1b * q1b)
                + (d[1] + d[2]) * (q1a * q2a + q1b * q2b)
                + d[3] * (q2a * q2a + q2b * q2b) + pp;
      }
      if (w == 0) {
        #pragma unroll
        for (int off = 32; off; off >>= 1) contrib += __shfl_down(contrib, off);
        if (lane == 0) atomicAdd(out + b, contrib);
      }
    }
  }
}

// ---------------------------------------------------------------------------
extern "C" void kernel_launch(void* const* d_in, const int* in_sizes, int n_in,
                              void* d_out, int out_size, void* d_ws, size_t ws_size,
                              hipStream_t stream) {
  const float* x   = (const float*)d_in[0];
  const float* L   = (const float*)d_in[1];
  const float* Aq  = (const float*)d_in[2];
  const float* Ak  = (const float*)d_in[3];
  const float* Av  = (const float*)d_in[4];
  const float* Aq1 = (const float*)d_in[5];
  const float* Ak1 = (const float*)d_in[6];
  const float* Av1 = (const float*)d_in[7];
  const float* Aq5 = (const float*)d_in[8];
  const float* Ak5 = (const float*)d_in[9];
  const float* Av5 = (const float*)d_in[10];
  const float* Ao  = (const float*)d_in[11];
  const float* Ao1 = (const float*)d_in[12];
  const float* Ao5 = (const float*)d_in[13];

  char* ws = (char*)d_ws;
  uint32_t* bar = (uint32_t*)ws;
  f16* Wcat  = (f16*)(ws + 256);
  f16* Qtg   = (f16*)(ws + 860416);
  f16* Ktg   = (f16*)(ws + 2957568);
  f16* Vgg   = (f16*)(ws + 5054720);
  f16* MbufA = (f16*)(ws + 7151872);
  f16* MbufB = (f16*)(ws + 9249024);
  float* out = (float*)d_out;

  prep_kernel<<<97, 256, 0, stream>>>(Aq, Ak, Av, Wcat, bar, out);
  qkv1_kernel<<<dim3(4, 64), 512, 0, stream>>>(x, Wcat, Qtg, Ktg, Vgg);
  attn_fused_kernel<<<dim3(4, 64), 1024, 0, stream>>>(x, L,
      Aq1, Ak1, Av1, Aq5, Ak5, Av5, Ao, Ao1, Ao5,
      Qtg, Ktg, Vgg, MbufA, MbufB, bar, out);
}